// Round 10
// baseline (346.523 us; speedup 1.0000x reference)
//
#include <hip/hip_runtime.h>

#define BN_EPS 1e-5f
#define MAXBINS 128   // bins of 512 rows; requires N <= 65536 (col packs in 16 bits)

typedef __attribute__((ext_vector_type(8))) short bf16x8;
typedef __attribute__((ext_vector_type(4))) float f32x4;

__device__ __forceinline__ ushort f2bf(float f) {
  uint u = __float_as_uint(f);
  u += 0x7fffu + ((u >> 16) & 1u);
  return (ushort)(u >> 16);
}
__device__ __forceinline__ float bf2f(ushort u) {
  return __uint_as_float((uint)u << 16);
}
__device__ __forceinline__ uint pack2bf(float a, float b) {
  return (uint)f2bf(a) | ((uint)f2bf(b) << 16);
}
// acc[0..7] += v * bf16x8(wv)
__device__ __forceinline__ void fma8(float acc[8], uint4 wv, float v) {
  acc[0] += v * __uint_as_float(wv.x << 16);
  acc[1] += v * __uint_as_float(wv.x & 0xffff0000u);
  acc[2] += v * __uint_as_float(wv.y << 16);
  acc[3] += v * __uint_as_float(wv.y & 0xffff0000u);
  acc[4] += v * __uint_as_float(wv.z << 16);
  acc[5] += v * __uint_as_float(wv.z & 0xffff0000u);
  acc[6] += v * __uint_as_float(wv.w << 16);
  acc[7] += v * __uint_as_float(wv.w & 0xffff0000u);
}

// ---------------------------------------------------------------------------
// One-time prep: bf16 transposed weight tables + BN scale/shift.
//   Wet[col][k] col<64,k<512 = We^T
//   Wtg[col][k] col<128,k<192 = [Wf[0:192] | Wf[192:320](k>=64) |
//                                Wf[320:448](k>=64) | 0]^T
//   bnsc[c]/bnsh[c] c<128 : BN scale/shift
// ---------------------------------------------------------------------------
__global__ __launch_bounds__(256) void prep_weights(
    const float* __restrict__ We, const float* __restrict__ Wf,
    const float* __restrict__ gamma, const float* __restrict__ beta,
    const float* __restrict__ mean, const float* __restrict__ var,
    ushort* __restrict__ Wet, ushort* __restrict__ Wtg,
    float* __restrict__ bnsc, float* __restrict__ bnsh) {
  int i = blockIdx.x * 256 + threadIdx.x;
  if (i < 32768) {
    int col = i >> 9, k = i & 511;
    Wet[(size_t)col * 512 + k] = f2bf(We[(size_t)k * 64 + col]);
  } else if (i < 32768 + 24576) {
    int j = i - 32768;
    int col = j / 192, k = j % 192;
    float v = 0.f;
    if (col < 40)       v = Wf[(size_t)k * 40 + col];
    else if (col < 80)  { if (k >= 64) v = Wf[(size_t)(128 + k) * 40 + (col - 40)]; }
    else if (col < 120) { if (k >= 64) v = Wf[(size_t)(256 + k) * 40 + (col - 80)]; }
    Wtg[(size_t)col * 192 + k] = f2bf(v);
  } else if (i < 32768 + 24576 + 128) {
    int c = i - 32768 - 24576;
    float s = gamma[c] * rsqrtf(var[c] + BN_EPS);
    bnsc[c] = s;
    bnsh[c] = beta[c] - mean[c] * s;
  }
}

// ---------------------------------------------------------------------------
// Embed via MFMA, no LDS: [hbA|hbB] = bf16( relu(x @ We + b) ), split [N][32].
// ---------------------------------------------------------------------------
__global__ __launch_bounds__(256) void embed_mfma(
    const float* __restrict__ x, const ushort* __restrict__ Wet,
    const float* __restrict__ b, ushort* __restrict__ hbA,
    ushort* __restrict__ hbB, int N) {
  const int tid  = threadIdx.x;
  const int wv   = tid >> 6;
  const int lane = tid & 63;
  const int m16  = lane & 15;
  const int kg   = lane >> 4;
  const int row0 = blockIdx.x * 128 + wv * 32;

  f32x4 acc[2][4];
#pragma unroll
  for (int i = 0; i < 2; ++i)
#pragma unroll
    for (int t = 0; t < 4; ++t) acc[i][t] = (f32x4){0.f, 0.f, 0.f, 0.f};

#pragma unroll 4
  for (int ks = 0; ks < 16; ++ks) {
    const int kk = ks * 32 + kg * 8;
    bf16x8 afr[2];
#pragma unroll
    for (int i = 0; i < 2; ++i) {
      int grow = row0 + i * 16 + m16;
      grow = (grow < N) ? grow : (N - 1);
      const float* ap = x + (size_t)grow * 512 + kk;
      float4 lo = *reinterpret_cast<const float4*>(ap);
      float4 hi = *reinterpret_cast<const float4*>(ap + 4);
      uint4 pk;
      pk.x = pack2bf(lo.x, lo.y); pk.y = pack2bf(lo.z, lo.w);
      pk.z = pack2bf(hi.x, hi.y); pk.w = pack2bf(hi.z, hi.w);
      afr[i] = *reinterpret_cast<const bf16x8*>(&pk);
    }
#pragma unroll
    for (int t = 0; t < 4; ++t) {
      bf16x8 bfr = *reinterpret_cast<const bf16x8*>(
          Wet + (size_t)(t * 16 + m16) * 512 + kk);
      acc[0][t] = __builtin_amdgcn_mfma_f32_16x16x32_bf16(afr[0], bfr, acc[0][t], 0, 0, 0);
      acc[1][t] = __builtin_amdgcn_mfma_f32_16x16x32_bf16(afr[1], bfr, acc[1][t], 0, 0, 0);
    }
  }

#pragma unroll
  for (int i = 0; i < 2; ++i) {
    const int rbase = row0 + i * 16 + kg * 4;
#pragma unroll
    for (int t = 0; t < 4; ++t) {
      const int col = t * 16 + m16;
      const float bias = b[col];
#pragma unroll
      for (int reg = 0; reg < 4; ++reg) {
        int gr = rbase + reg;
        if (gr < N) {
          ushort v = f2bf(fmaxf(acc[i][t][reg] + bias, 0.f));
          if (col < 32) hbA[(size_t)gr * 32 + col] = v;
          else          hbB[(size_t)gr * 32 + (col - 32)] = v;
        }
      }
    }
  }
}

// ---------------------------------------------------------------------------
// CSR build, two-level binned (bin = row>>9)
// ---------------------------------------------------------------------------
__global__ __launch_bounds__(256) void bin_hist(
    const int* __restrict__ rows, int* __restrict__ gbin, int E, int nbins) {
  __shared__ int lb[MAXBINS];
  const int tid = threadIdx.x;
  if (tid < nbins) lb[tid] = 0;
  __syncthreads();
  const int stride = gridDim.x * blockDim.x;
  for (int i = blockIdx.x * blockDim.x + tid; i < E; i += stride)
    atomicAdd(&lb[rows[i] >> 9], 1);
  __syncthreads();
  if (tid < nbins && lb[tid]) atomicAdd(&gbin[tid], lb[tid]);
}

__device__ __forceinline__ void scan_bins_dev(
    const int* gbin, int* gbase, int* gcur, int nbins, int lane) {
  int carry = 0;
  for (int ch = 0; ch * 64 < nbins; ++ch) {
    int idx = ch * 64 + lane;
    int v = (idx < nbins) ? gbin[idx] : 0;
    int inc = v;
#pragma unroll
    for (int off = 1; off < 64; off <<= 1) {
      int y = __shfl_up(inc, off);
      if (lane >= off) inc += y;
    }
    int ex = carry + inc - v;
    if (idx < nbins) { gbase[idx] = ex; gcur[idx] = ex; }
    carry += __shfl(inc, 63);
  }
}

__global__ __launch_bounds__(64) void bin_scan(
    const int* __restrict__ gbin1, int* __restrict__ gbase1, int* __restrict__ gcur1,
    const int* __restrict__ gbin2, int* __restrict__ gbase2, int* __restrict__ gcur2,
    int nbins) {
  int lane = threadIdx.x;
  scan_bins_dev(gbin1, gbase1, gcur1, nbins, lane);
  scan_bins_dev(gbin2, gbase2, gcur2, nbins, lane);
}

// Staging record: int2( col | (row&511)<<16 , val_bits_f32 ).
__global__ __launch_bounds__(256) void bin_scatter(
    const int* __restrict__ rows, const int* __restrict__ cols,
    const float* __restrict__ vals, int E, int* __restrict__ gcur,
    int2* __restrict__ S, int nbins) {
  __shared__ int lcnt[MAXBINS];
  __shared__ int lcur[MAXBINS];
  const int tid = threadIdx.x;
  for (int e0 = blockIdx.x * 2048; e0 < E; e0 += gridDim.x * 2048) {
    int i0 = e0 + tid * 8;
    int r[8], c[8], vb[8];
    if (i0 + 8 <= E) {
      int4 a = *reinterpret_cast<const int4*>(rows + i0);
      int4 b = *reinterpret_cast<const int4*>(rows + i0 + 4);
      r[0]=a.x; r[1]=a.y; r[2]=a.z; r[3]=a.w; r[4]=b.x; r[5]=b.y; r[6]=b.z; r[7]=b.w;
      a = *reinterpret_cast<const int4*>(cols + i0);
      b = *reinterpret_cast<const int4*>(cols + i0 + 4);
      c[0]=a.x; c[1]=a.y; c[2]=a.z; c[3]=a.w; c[4]=b.x; c[5]=b.y; c[6]=b.z; c[7]=b.w;
      a = *reinterpret_cast<const int4*>(vals + i0);
      b = *reinterpret_cast<const int4*>(vals + i0 + 4);
      vb[0]=a.x; vb[1]=a.y; vb[2]=a.z; vb[3]=a.w; vb[4]=b.x; vb[5]=b.y; vb[6]=b.z; vb[7]=b.w;
    } else {
#pragma unroll
      for (int t = 0; t < 8; ++t) {
        int i = i0 + t;
        bool ok = i < E;
        r[t]  = ok ? rows[i] : -1;
        c[t]  = ok ? cols[i] : 0;
        vb[t] = ok ? __float_as_int(vals[i]) : 0;
      }
    }
    if (tid < nbins) lcnt[tid] = 0;
    __syncthreads();
#pragma unroll
    for (int t = 0; t < 8; ++t)
      if (r[t] >= 0) atomicAdd(&lcnt[r[t] >> 9], 1);
    __syncthreads();
    if (tid < nbins) {
      int n = lcnt[tid];
      lcur[tid] = n ? atomicAdd(&gcur[tid], n) : 0;
    }
    __syncthreads();
#pragma unroll
    for (int t = 0; t < 8; ++t) {
      if (r[t] >= 0) {
        int pos = atomicAdd(&lcur[r[t] >> 9], 1);
        S[pos] = make_int2(c[t] | ((r[t] & 511) << 16), vb[t]);
      }
    }
    __syncthreads();
  }
}

// One block per (graph, bin). Final edge record: uint( col | bf16(val)<<16 ).
__global__ __launch_bounds__(256) void csr_finalize(
    const int2* __restrict__ S1, const int* __restrict__ gbase1,
    int* __restrict__ rp1, uint* __restrict__ Eo1, int Etot1,
    const int2* __restrict__ S2, const int* __restrict__ gbase2,
    int* __restrict__ rp2, uint* __restrict__ Eo2, int Etot2,
    int N, int nbins) {
  __shared__ int cnt[512];
  __shared__ int cur[512];
  const int tid = threadIdx.x;
  const int b = blockIdx.x % nbins;
  const int g = blockIdx.x / nbins;
  const int2* S     = g ? S2 : S1;
  const int* gbase  = g ? gbase2 : gbase1;
  int* rp           = g ? rp2 : rp1;
  uint* Eo          = g ? Eo2 : Eo1;
  const int Etot    = g ? Etot2 : Etot1;

  const int base = gbase[b];
  const int end  = (b + 1 < nbins) ? gbase[b + 1] : Etot;
  const int r0   = b << 9;
  const int nrows = min(512, N - r0);

  for (int l = tid; l < 512; l += 256) cnt[l] = 0;
  __syncthreads();
  for (int j = base + tid; j < end; j += 256)
    atomicAdd(&cnt[S[j].x >> 16], 1);
  __syncthreads();
  if (tid < 64) {
    int carry = 0;
#pragma unroll
    for (int ch = 0; ch < 8; ++ch) {
      int v = cnt[ch * 64 + tid];
      int inc = v;
#pragma unroll
      for (int off = 1; off < 64; off <<= 1) {
        int y = __shfl_up(inc, off);
        if (tid >= off) inc += y;
      }
      inc += carry;
      cnt[ch * 64 + tid] = inc;
      carry = __shfl(inc, 63);
    }
  }
  __syncthreads();
  for (int l = tid; l < 512; l += 256)
    cur[l] = base + ((l > 0) ? cnt[l - 1] : 0);
  for (int l = tid; l < nrows; l += 256)
    rp[r0 + l + 1] = base + cnt[l];
  if (b == 0 && tid == 0) rp[0] = 0;
  __syncthreads();
  for (int j = base + tid; j < end; j += 256) {
    int2 m = S[j];
    int pos = atomicAdd(&cur[m.x >> 16], 1);
    Eo[pos] = (uint)(m.x & 0xffff) | ((uint)f2bf(__int_as_float(m.y)) << 16);
  }
}

// ---------------------------------------------------------------------------
// Conv1 gather + fused BN, two feature passes (each gather table 3.2MB -> L2).
// Pass p: 16 edges/VMEM (sub=lane>>2, q=lane&3), MLP=2, 32-edge chunks.
// ---------------------------------------------------------------------------
__global__ __launch_bounds__(256) void conv1_gather(
    const ushort* __restrict__ hbA, const ushort* __restrict__ hbB,
    const int* __restrict__ rp1, const uint* __restrict__ E1,
    const int* __restrict__ rp2, const uint* __restrict__ E2,
    const float* __restrict__ bnsc, const float* __restrict__ bnsh,
    ushort* __restrict__ h1b, int N, int nwaves) {
  const int wid  = (blockIdx.x * blockDim.x + threadIdx.x) >> 6;
  const int lane = threadIdx.x & 63;
  const int sub  = lane >> 2;   // 16 edge slots
  const int q    = lane & 3;    // 4 feature groups of 8

  for (int r = wid; r < N; r += nwaves) {
    const int s1 = rp1[r], e1 = rp1[r + 1];
    const int s2 = rp2[r], e2 = rp2[r + 1];
#pragma unroll
    for (int p = 0; p < 2; ++p) {
      const ushort* src = p ? hbB : hbA;
      float acc1[8] = {0, 0, 0, 0, 0, 0, 0, 0};
      float acc2[8] = {0, 0, 0, 0, 0, 0, 0, 0};
      for (int j0 = s1; j0 < e1; j0 += 32) {
        int j = j0 + sub;
        uint m0 = (j      < e1) ? E1[j]      : 0u;
        uint m1 = (j + 16 < e1) ? E1[j + 16] : 0u;
        uint4 w0 = *reinterpret_cast<const uint4*>(src + (size_t)(m0 & 0xffffu) * 32 + q * 8);
        uint4 w1 = *reinterpret_cast<const uint4*>(src + (size_t)(m1 & 0xffffu) * 32 + q * 8);
        fma8(acc1, w0, __uint_as_float(m0 & 0xffff0000u));
        fma8(acc1, w1, __uint_as_float(m1 & 0xffff0000u));
      }
      for (int j0 = s2; j0 < e2; j0 += 32) {
        int j = j0 + sub;
        uint m0 = (j      < e2) ? E2[j]      : 0u;
        uint m1 = (j + 16 < e2) ? E2[j + 16] : 0u;
        uint4 w0 = *reinterpret_cast<const uint4*>(src + (size_t)(m0 & 0xffffu) * 32 + q * 8);
        uint4 w1 = *reinterpret_cast<const uint4*>(src + (size_t)(m1 & 0xffffu) * 32 + q * 8);
        fma8(acc2, w0, __uint_as_float(m0 & 0xffff0000u));
        fma8(acc2, w1, __uint_as_float(m1 & 0xffff0000u));
      }
#pragma unroll
      for (int mask = 4; mask <= 32; mask <<= 1) {
#pragma unroll
        for (int t = 0; t < 8; ++t) {
          acc1[t] += __shfl_xor(acc1[t], mask);
          acc2[t] += __shfl_xor(acc2[t], mask);
        }
      }
      if (lane < 4) {
        const int f = p * 32 + q * 8;
        float4 scA0 = *reinterpret_cast<const float4*>(bnsc + f);
        float4 scA1 = *reinterpret_cast<const float4*>(bnsc + f + 4);
        float4 shA0 = *reinterpret_cast<const float4*>(bnsh + f);
        float4 shA1 = *reinterpret_cast<const float4*>(bnsh + f + 4);
        float4 scB0 = *reinterpret_cast<const float4*>(bnsc + 64 + f);
        float4 scB1 = *reinterpret_cast<const float4*>(bnsc + 64 + f + 4);
        float4 shB0 = *reinterpret_cast<const float4*>(bnsh + 64 + f);
        float4 shB1 = *reinterpret_cast<const float4*>(bnsh + 64 + f + 4);
        uint4 p1, p2;
        p1.x = pack2bf(acc1[0] * scA0.x + shA0.x, acc1[1] * scA0.y + shA0.y);
        p1.y = pack2bf(acc1[2] * scA0.z + shA0.z, acc1[3] * scA0.w + shA0.w);
        p1.z = pack2bf(acc1[4] * scA1.x + shA1.x, acc1[5] * scA1.y + shA1.y);
        p1.w = pack2bf(acc1[6] * scA1.z + shA1.z, acc1[7] * scA1.w + shA1.w);
        p2.x = pack2bf(acc2[0] * scB0.x + shB0.x, acc2[1] * scB0.y + shB0.y);
        p2.y = pack2bf(acc2[2] * scB0.z + shB0.z, acc2[3] * scB0.w + shB0.w);
        p2.z = pack2bf(acc2[4] * scB1.x + shB1.x, acc2[5] * scB1.y + shB1.y);
        p2.w = pack2bf(acc2[6] * scB1.z + shB1.z, acc2[7] * scB1.w + shB1.w);
        ushort* dst = h1b + (size_t)r * 128 + p * 32 + q * 8;
        *reinterpret_cast<uint4*>(dst)      = p1;
        *reinterpret_cast<uint4*>(dst + 64) = p2;
      }
    }
  }
}

// ---------------------------------------------------------------------------
// MFMA dense tail, no LDS: A = [hbA|hbB|h1b] (N x 192 bf16), B from Wtg (L2).
//   cols 0:40 -> out (f32,+bias); 40:80 -> g1A/g1B; 80:120 -> g2A/g2B (bf16)
// ---------------------------------------------------------------------------
__global__ __launch_bounds__(256) void dense_tail_mfma(
    const ushort* __restrict__ hbA, const ushort* __restrict__ hbB,
    const ushort* __restrict__ h1b,
    const ushort* __restrict__ Wtg, const float* __restrict__ bfin,
    float* __restrict__ out,
    ushort* __restrict__ g1A, ushort* __restrict__ g1B,
    ushort* __restrict__ g2A, ushort* __restrict__ g2B, int N) {
  const int tid  = threadIdx.x;
  const int wv   = tid >> 6;
  const int lane = tid & 63;
  const int m16  = lane & 15;
  const int kg   = lane >> 4;
  const int row0 = blockIdx.x * 128;

  f32x4 acc[2][8];
#pragma unroll
  for (int i = 0; i < 2; ++i)
#pragma unroll
    for (int t = 0; t < 8; ++t) acc[i][t] = (f32x4){0.f, 0.f, 0.f, 0.f};

#pragma unroll
  for (int ks = 0; ks < 6; ++ks) {
    const int kk = ks * 32 + kg * 8;
    bf16x8 afr[2];
#pragma unroll
    for (int i = 0; i < 2; ++i) {
      int grow = row0 + wv * 32 + i * 16 + m16;
      grow = (grow < N) ? grow : (N - 1);
      const ushort* ap;
      if (ks == 0)      ap = hbA + (size_t)grow * 32 + kk;
      else if (ks == 1) ap = hbB + (size_t)grow * 32 + (kk - 32);
      else              ap = h1b + (size_t)grow * 128 + (kk - 64);
      afr[i] = *reinterpret_cast<const bf16x8*>(ap);
    }
#pragma unroll
    for (int t = 0; t < 8; ++t) {
      bf16x8 bfr = *reinterpret_cast<const bf16x8*>(
          Wtg + (size_t)(t * 16 + m16) * 192 + kk);
      acc[0][t] = __builtin_amdgcn_mfma_f32_16x16x32_bf16(afr[0], bfr, acc[0][t], 0, 0, 0);
      acc[1][t] = __builtin_amdgcn_mfma_f32_16x16x32_bf16(afr[1], bfr, acc[1][t], 0, 0, 0);
    }
  }

#pragma unroll
  for (int i = 0; i < 2; ++i) {
    const int rbase = row0 + wv * 32 + i * 16 + kg * 4;
#pragma unroll
    for (int t = 0; t < 8; ++t) {
      const int col = t * 16 + m16;
      if (col >= 120) continue;
      const float bias = (col < 40) ? bfin[col] : 0.f;
#pragma unroll
      for (int reg = 0; reg < 4; ++reg) {
        int gr = rbase + reg;
        if (gr < N) {
          float v = acc[i][t][reg];
          if (col < 40) {
            out[(size_t)gr * 40 + col] = v + bias;
          } else if (col < 80) {
            int f = col - 40;
            if (f < 32) g1A[(size_t)gr * 32 + f] = f2bf(v);
            else        g1B[(size_t)gr * 8 + (f - 32)] = f2bf(v);
          } else {
            int f = col - 80;
            if (f < 32) g2A[(size_t)gr * 32 + f] = f2bf(v);
            else        g2B[(size_t)gr * 8 + (f - 32)] = f2bf(v);
          }
        }
      }
    }
  }
}

// ---------------------------------------------------------------------------
// Final add, two passes with L2-resident tables:
//  pass A: feats 0-31 from g1A/g2A (16 edges/inst); pass B: feats 32-39 from
//  g1B/g2B (64 edges/inst). Both graphs accumulate into one register set.
// ---------------------------------------------------------------------------
__global__ __launch_bounds__(256) void final_add_kernel(
    const ushort* __restrict__ g1A, const ushort* __restrict__ g1B,
    const ushort* __restrict__ g2A, const ushort* __restrict__ g2B,
    const int* __restrict__ rp1, const uint* __restrict__ E1,
    const int* __restrict__ rp2, const uint* __restrict__ E2,
    float* __restrict__ out, int N, int nwaves) {
  const int wid  = (blockIdx.x * blockDim.x + threadIdx.x) >> 6;
  const int lane = threadIdx.x & 63;
  const int sub  = lane >> 2;
  const int q    = lane & 3;

  for (int r = wid; r < N; r += nwaves) {
    const int s1 = rp1[r], e1 = rp1[r + 1];
    const int s2 = rp2[r], e2 = rp2[r + 1];

    // ---- pass A: features 0..31 ----
    float a[8] = {0, 0, 0, 0, 0, 0, 0, 0};
    for (int j0 = s1; j0 < e1; j0 += 32) {
      int j = j0 + sub;
      uint m0 = (j      < e1) ? E1[j]      : 0u;
      uint m1 = (j + 16 < e1) ? E1[j + 16] : 0u;
      uint4 w0 = *reinterpret_cast<const uint4*>(g1A + (size_t)(m0 & 0xffffu) * 32 + q * 8);
      uint4 w1 = *reinterpret_cast<const uint4*>(g1A + (size_t)(m1 & 0xffffu) * 32 + q * 8);
      fma8(a, w0, __uint_as_float(m0 & 0xffff0000u));
      fma8(a, w1, __uint_as_float(m1 & 0xffff0000u));
    }
    for (int j0 = s2; j0 < e2; j0 += 32) {
      int j = j0 + sub;
      uint m0 = (j      < e2) ? E2[j]      : 0u;
      uint m1 = (j + 16 < e2) ? E2[j + 16] : 0u;
      uint4 w0 = *reinterpret_cast<const uint4*>(g2A + (size_t)(m0 & 0xffffu) * 32 + q * 8);
      uint4 w1 = *reinterpret_cast<const uint4*>(g2A + (size_t)(m1 & 0xffffu) * 32 + q * 8);
      fma8(a, w0, __uint_as_float(m0 & 0xffff0000u));
      fma8(a, w1, __uint_as_float(m1 & 0xffff0000u));
    }
#pragma unroll
    for (int mask = 4; mask <= 32; mask <<= 1)
#pragma unroll
      for (int t = 0; t < 8; ++t) a[t] += __shfl_xor(a[t], mask);

    // ---- pass B: features 32..39 (one edge per lane) ----
    float bb[8] = {0, 0, 0, 0, 0, 0, 0, 0};
    for (int j0 = s1; j0 < e1; j0 += 64) {
      int j = j0 + lane;
      uint m = (j < e1) ? E1[j] : 0u;
      uint4 w = *reinterpret_cast<const uint4*>(g1B + (size_t)(m & 0xffffu) * 8);
      fma8(bb, w, __uint_as_float(m & 0xffff0000u));
    }
    for (int j0 = s2; j0 < e2; j0 += 64) {
      int j = j0 + lane;
      uint m = (j < e2) ? E2[j] : 0u;
      uint4 w = *reinterpret_cast<const uint4*>(g2B + (size_t)(m & 0xffffu) * 8);
      fma8(bb, w, __uint_as_float(m & 0xffff0000u));
    }
#pragma unroll
    for (int mask = 1; mask <= 32; mask <<= 1)
#pragma unroll
      for (int t = 0; t < 8; ++t) bb[t] += __shfl_xor(bb[t], mask);

    if (lane < 4) {
      float* p = out + (size_t)r * 40 + q * 8;
      float4 o0 = *reinterpret_cast<const float4*>(p);
      float4 o1 = *reinterpret_cast<const float4*>(p + 4);
      o0.x += a[0]; o0.y += a[1]; o0.z += a[2]; o0.w += a[3];
      o1.x += a[4]; o1.y += a[5]; o1.z += a[6]; o1.w += a[7];
      *reinterpret_cast<float4*>(p)     = o0;
      *reinterpret_cast<float4*>(p + 4) = o1;
    }
    if (lane == 0) {
      float* p = out + (size_t)r * 40 + 32;
      float4 o0 = *reinterpret_cast<const float4*>(p);
      float4 o1 = *reinterpret_cast<const float4*>(p + 4);
      o0.x += bb[0]; o0.y += bb[1]; o0.z += bb[2]; o0.w += bb[3];
      o1.x += bb[4]; o1.y += bb[5]; o1.z += bb[6]; o1.w += bb[7];
      *reinterpret_cast<float4*>(p)     = o0;
      *reinterpret_cast<float4*>(p + 4) = o1;
    }
  }
}

// ---------------------------------------------------------------------------
extern "C" void kernel_launch(void* const* d_in, const int* in_sizes, int n_in,
                              void* d_out, int out_size, void* d_ws, size_t ws_size,
                              hipStream_t stream) {
  const float* x     = (const float*)d_in[0];
  const int*   a1r   = (const int*)d_in[1];
  const int*   a1c   = (const int*)d_in[2];
  const float* a1v   = (const float*)d_in[3];
  const int*   a2r   = (const int*)d_in[4];
  const int*   a2c   = (const int*)d_in[5];
  const float* a2v   = (const float*)d_in[6];
  const float* We    = (const float*)d_in[7];
  const float* be    = (const float*)d_in[8];
  const float* gamma = (const float*)d_in[9];
  const float* beta  = (const float*)d_in[10];
  const float* mean  = (const float*)d_in[11];
  const float* var   = (const float*)d_in[12];
  const float* Wf    = (const float*)d_in[13];
  const float* bf    = (const float*)d_in[14];
  float* out = (float*)d_out;

  const int N  = in_sizes[0] / 512;
  const int E1 = in_sizes[1];
  const int E2 = in_sizes[4];
  const int nbins = (N + 511) >> 9;   // requires N <= 65536

  char* p = (char*)d_ws;
  auto alloc = [&](size_t bytes) {
    char* q = p; p += (bytes + 255) & ~(size_t)255; return q;
  };
  ushort* hbA  = (ushort*)alloc((size_t)N * 32 * 2);
  ushort* hbB  = (ushort*)alloc((size_t)N * 32 * 2);
  ushort* h1b  = (ushort*)alloc((size_t)N * 128 * 2);
  ushort* g1A  = (ushort*)alloc((size_t)N * 32 * 2);
  ushort* g1B  = (ushort*)alloc((size_t)N * 8 * 2);
  ushort* g2A  = (ushort*)alloc((size_t)N * 32 * 2);
  ushort* g2B  = (ushort*)alloc((size_t)N * 8 * 2);
  ushort* Wet  = (ushort*)alloc((size_t)64 * 512 * 2);
  ushort* Wtg  = (ushort*)alloc((size_t)128 * 192 * 2);
  float*  bnsc = (float*) alloc(128 * 4);
  float*  bnsh = (float*) alloc(128 * 4);
  int*    rp1  = (int*)   alloc(((size_t)N + 1) * 4);
  int*    rp2  = (int*)   alloc(((size_t)N + 1) * 4);
  uint*   E1s  = (uint*)  alloc((size_t)E1 * 4);
  uint*   E2s  = (uint*)  alloc((size_t)E2 * 4);
  int2*   S1   = (int2*)  alloc((size_t)E1 * 8);
  int2*   S2   = (int2*)  alloc((size_t)E2 * 8);
  int*    gbin1  = (int*) alloc(MAXBINS * 4);
  int*    gbin2  = (int*) alloc(MAXBINS * 4);
  int*    gbase1 = (int*) alloc(MAXBINS * 4);
  int*    gbase2 = (int*) alloc(MAXBINS * 4);
  int*    gcur1  = (int*) alloc(MAXBINS * 4);
  int*    gcur2  = (int*) alloc(MAXBINS * 4);

  hipMemsetAsync(gbin1, 0, (size_t)2 * MAXBINS * 4 + 256, stream);

  // one-time weight transpose + BN fold
  prep_weights<<<(32768 + 24576 + 128 + 255) / 256, 256, 0, stream>>>(
      We, Wf, gamma, beta, mean, var, Wet, Wtg, bnsc, bnsh);

  // embed via MFMA (no LDS; B from Wet), split hbA/hbB output
  embed_mfma<<<(N + 127) / 128, 256, 0, stream>>>(x, Wet, be, hbA, hbB, N);

  // binned CSR build
  bin_hist<<<256, 256, 0, stream>>>(a1r, gbin1, E1, nbins);
  bin_hist<<<256, 256, 0, stream>>>(a2r, gbin2, E2, nbins);
  bin_scan<<<1, 64, 0, stream>>>(gbin1, gbase1, gcur1, gbin2, gbase2, gcur2, nbins);
  bin_scatter<<<256, 256, 0, stream>>>(a1r, a1c, a1v, E1, gcur1, S1, nbins);
  bin_scatter<<<256, 256, 0, stream>>>(a2r, a2c, a2v, E2, gcur2, S2, nbins);
  csr_finalize<<<2 * nbins, 256, 0, stream>>>(
      S1, gbase1, rp1, E1s, E1, S2, gbase2, rp2, E2s, E2, N, nbins);

  // conv1 (two-pass L2-resident gather) + fused BN -> bf16 h1b
  const int NW = 2048 * 4;
  conv1_gather<<<2048, 256, 0, stream>>>(
      hbA, hbB, rp1, E1s, rp2, E2s, bnsc, bnsh, h1b, N, NW);

  // MFMA dense tail (no LDS): out base + split g tables in one pass
  dense_tail_mfma<<<(N + 127) / 128, 256, 0, stream>>>(
      hbA, hbB, h1b, Wtg, bf, out, g1A, g1B, g2A, g2B, N);

  // out += A1@g1 + A2@g2 (two-pass L2-resident gather)
  final_add_kernel<<<2048, 256, 0, stream>>>(
      g1A, g1B, g2A, g2B, rp1, E1s, rp2, E2s, out, N, NW);
}